// Round 3
// baseline (214.222 us; speedup 1.0000x reference)
//
#include <hip/hip_runtime.h>
#include <math.h>

// ---------------------------------------------------------------------------
// RoutingNet round 13:
//  k_main: icg-in-lane remap. All ic-partial reductions (L1/L2/L3/L4/e) are
//    now in-wave __shfl_xor sums (ic interleaved: ic = icg + nIcg*ii), which
//    removes L1R + all RED exchanges, ~6 barriers, and the half-idle reduce
//    phases. LDS 154->113 KB. L1 left-column read via aligned float4 at rp-4
//    (.w) instead of the 8-way-conflicted scalar rp[-1].
//  k_prep: coalesced-read / scattered-write transposes (reads stall, writes
//    don't; L2 absorbs 4B scattered writes, dest fully written -> clean WB).
//  Tail unchanged from R10/R12.
// ---------------------------------------------------------------------------

#define BN_SCALE rsqrtf(1.0f + 1e-5f)

// ws offsets (floats)
#define OFF_FEATS 0
#define OFF_E     64000
#define OFF_S     89600
#define OFF_T1    91136
#define OFF_PROTO 347136
#define OFF_W1T   349696
#define OFF_W2T   354304
#define OFF_W3T   372736
#define OFF_W4T   446464
#define OFF_TWT   741376

// ---- Kernel 1: transposes (coalesced reads) + zero t1,s. 2793 blocks ----
__global__ void k_prep(const float* __restrict__ w1, const float* __restrict__ w2,
                       const float* __restrict__ w3, const float* __restrict__ w4,
                       const float* __restrict__ tw, float* __restrict__ ws) {
  float* w1t = ws + OFF_W1T;
  float* w2t = ws + OFF_W2T;
  float* w3t = ws + OFF_W3T;
  float* w4t = ws + OFF_W4T;
  float* twt = ws + OFF_TWT;
  int i = blockIdx.x * 256 + threadIdx.x;
  if (i < 4608) {                       // w1: 32x16x9, read natural
    int oc = i / 144, r = i % 144;
    int ic = r / 9, tap = r % 9;
    w1t[(ic * 9 + tap) * 32 + oc] = w1[i];
  } else if (i < 23040) {               // w2: 64x32x9
    int m = i - 4608;
    int oc = m / 288, r = m % 288;
    int ic = r / 9, tap = r % 9;
    w2t[(ic * 9 + tap) * 64 + oc] = w2[m];
  } else if (i < 96768) {               // w3: 128x64x9
    int m = i - 23040;
    int oc = m / 576, r = m % 576;
    int ic = r / 9, tap = r % 9;
    w3t[(ic * 9 + tap) * 128 + oc] = w3[m];
  } else if (i < 391680) {              // w4: 256x128x9
    int m = i - 96768;
    int oc = m / 1152, r = m % 1152;
    int ic = r / 9, tap = r % 9;
    w4t[(ic * 9 + tap) * 256 + oc] = w4[m];
  } else if (i < 457216) {              // tw: 256x256, twt[d][c] = tw[c][d]
    int m = i - 391680;
    int r = m >> 8, s = m & 255;
    twt[s * 256 + r] = tw[m];
  } else if (i < 713216) {
    ws[OFF_T1 + (i - 457216)] = 0.f;
  } else if (i < 714716) {
    ws[OFF_S + (i - 713216)] = 0.f;
  }
}

// ---- Kernel 2: whole CNN per image. 250 blocks x 1024 threads ----
__global__ void __launch_bounds__(1024, 4)
k_main(const float* __restrict__ sup, const float* __restrict__ qry,
       const float* __restrict__ w0, const float* __restrict__ g0, const float* __restrict__ b0,
       const float* __restrict__ g1, const float* __restrict__ b1,
       const float* __restrict__ g2, const float* __restrict__ b2,
       const float* __restrict__ g3, const float* __restrict__ b3,
       const float* __restrict__ g4, const float* __restrict__ b4,
       const float* __restrict__ tb, float* __restrict__ ws,
       float* __restrict__ feats_g, float* __restrict__ e_buf) {
  // layout (floats):
  //  [0,3968)      sa1  (32 oc x 10x12 padded, zero borders)
  //  [4096,7424)   sa2  (64 oc x 52)
  //  [7424,7936)   sa3
  //  [7936,8192)   sft
  //  [8192,8580)   gap (zeroed: absorbs a0p[-4..-1] stray f4 read)
  //  [8580,28164)  a0p (16 oc x 34x36, interior rows 1..32 cols 0..31,
  //                pad right cols 32..35 + rows 0,33)
  __shared__ __align__(16) float S[28164];   // 112.7 KB
  const float* w1t = ws + OFF_W1T;
  const float* w2t = ws + OFF_W2T;
  const float* w3t = ws + OFF_W3T;
  const float* w4t = ws + OFF_W4T;
  const float* twt = ws + OFF_TWT;
  const int img = blockIdx.x;
  const int t = threadIdx.x;
  const int lane = t & 63, wid = t >> 6;
  float* sa1 = S;
  float* sa2 = S + 4096;
  float* sa3 = S + 7424;
  float* sft = S + 7936;
  float* a0p = S + 8580;

  const float* in = (img < 100) ? (sup + (size_t)img * 16384)
                                : (qry + (size_t)(img - 100) * 16384);

  // zero everything (7041 b128s)
  {
    float4* S4 = (float4*)S;
    const float4 z4 = make_float4(0.f, 0.f, 0.f, 0.f);
    for (int i = t; i < 7041; i += 1024) S4[i] = z4;
  }
  __syncthreads();

  // ---- L0: direct-global, 2 oc per wave x half of pooled rows ----
  {
    const int ocp = wid & 7;            // oc pair: 2*ocp, 2*ocp+1
    const int rhalf = wid >> 3;         // pooled rows [16*rhalf, 16*rhalf+16)
    const int oc0 = 2 * ocp, oc1 = oc0 + 1;
    float wv0[9], wv1[9];
#pragma unroll
    for (int k = 0; k < 9; k++) { wv0[k] = w0[oc0 * 9 + k]; wv1[k] = w0[oc1 * 9 + k]; }
    const float sc0 = g0[oc0] * BN_SCALE, bs0 = b0[oc0];
    const float sc1 = g0[oc1] * BN_SCALE, bs1 = b0[oc1];
#pragma unroll
    for (int it2 = 0; it2 < 2; it2++) {
      const int s2 = rhalf * 128 + it2 * 64 + lane;   // strip id
      const int pr = s2 >> 3, pcq = s2 & 7;           // pooled row, 4-col strip
      float ac0[2][8], ac1[2][8];
#pragma unroll
      for (int j = 0; j < 8; j++) {
        ac0[0][j] = 0.f; ac0[1][j] = 0.f; ac1[0][j] = 0.f; ac1[1][j] = 0.f;
      }
#pragma unroll
      for (int d = 0; d < 5; d++) {
        const int ir = 4 * pr - 1 + d;                // only -1 possible OOB
        float x[17];                                  // cols 16*pcq-1 .. +15
        if (ir >= 0) {
          const float* rp = in + ir * 128 + 16 * pcq;
          float4 q0 = ((const float4*)rp)[0];
          float4 q1 = ((const float4*)rp)[1];
          float4 q2 = ((const float4*)rp)[2];
          float4 q3 = ((const float4*)rp)[3];
          x[0] = (pcq > 0) ? rp[-1] : 0.f;
          x[1] = q0.x;  x[2] = q0.y;  x[3] = q0.z;  x[4] = q0.w;
          x[5] = q1.x;  x[6] = q1.y;  x[7] = q1.z;  x[8] = q1.w;
          x[9] = q2.x;  x[10] = q2.y; x[11] = q2.z; x[12] = q2.w;
          x[13] = q3.x; x[14] = q3.y; x[15] = q3.z; x[16] = q3.w;
        } else {
#pragma unroll
          for (int k = 0; k < 17; k++) x[k] = 0.f;
        }
        if (d <= 2) {
          const int b9 = d * 3;
#pragma unroll
          for (int j = 0; j < 8; j++) {
            ac0[0][j] = fmaf(x[2 * j + 2], wv0[b9 + 2],
                        fmaf(x[2 * j + 1], wv0[b9 + 1],
                        fmaf(x[2 * j],     wv0[b9],     ac0[0][j])));
            ac1[0][j] = fmaf(x[2 * j + 2], wv1[b9 + 2],
                        fmaf(x[2 * j + 1], wv1[b9 + 1],
                        fmaf(x[2 * j],     wv1[b9],     ac1[0][j])));
          }
        }
        if (d >= 2) {
          const int b9 = (d - 2) * 3;
#pragma unroll
          for (int j = 0; j < 8; j++) {
            ac0[1][j] = fmaf(x[2 * j + 2], wv0[b9 + 2],
                        fmaf(x[2 * j + 1], wv0[b9 + 1],
                        fmaf(x[2 * j],     wv0[b9],     ac0[1][j])));
            ac1[1][j] = fmaf(x[2 * j + 2], wv1[b9 + 2],
                        fmaf(x[2 * j + 1], wv1[b9 + 1],
                        fmaf(x[2 * j],     wv1[b9],     ac1[1][j])));
          }
        }
      }
      {
        float v[4];
#pragma unroll
        for (int p = 0; p < 4; p++) {
          float m = fmaf(ac0[0][2 * p], sc0, bs0);
          m = fmaxf(m, fmaf(ac0[0][2 * p + 1], sc0, bs0));
          m = fmaxf(m, fmaf(ac0[1][2 * p], sc0, bs0));
          m = fmaxf(m, fmaf(ac0[1][2 * p + 1], sc0, bs0));
          v[p] = fmaxf(m, 0.f);
        }
        *(float4*)(a0p + oc0 * 1224 + (pr + 1) * 36 + 4 * pcq) =
            make_float4(v[0], v[1], v[2], v[3]);
#pragma unroll
        for (int p = 0; p < 4; p++) {
          float m = fmaf(ac1[0][2 * p], sc1, bs1);
          m = fmaxf(m, fmaf(ac1[0][2 * p + 1], sc1, bs1));
          m = fmaxf(m, fmaf(ac1[1][2 * p], sc1, bs1));
          m = fmaxf(m, fmaf(ac1[1][2 * p + 1], sc1, bs1));
          v[p] = fmaxf(m, 0.f);
        }
        *(float4*)(a0p + oc1 * 1224 + (pr + 1) * 36 + 4 * pcq) =
            make_float4(v[0], v[1], v[2], v[3]);
      }
    }
  }
  __syncthreads();

  // ---- L1: icg in lane bit 5 (ic = icg + 2*ii), shuffle reduce ----
  {
    const int w = t >> 6;
    const int ocg = w >> 1, posh = w & 1;
    const int posl = lane & 31, icg = lane >> 5;
    const int pos = posh * 32 + posl;
    const int py = pos >> 3, px = pos & 7;
    float acc[4][4];
#pragma unroll
    for (int j = 0; j < 4; j++)
#pragma unroll
      for (int p = 0; p < 4; p++) acc[j][p] = 0.f;
#pragma unroll 2
    for (int ii = 0; ii < 8; ii++) {
      const int ic = icg + 2 * ii;
      float win[25];
      const float* rb = a0p + ic * 1224 + 4 * py * 36 + 4 * px;
#pragma unroll
      for (int d = 0; d < 5; d++) {
        float4 a = *(const float4*)(rb + d * 36 - 4);   // cols 4px-4..4px-1
        float4 b = *(const float4*)(rb + d * 36);       // cols 4px..4px+3
        win[d * 5 + 0] = a.w;
        win[d * 5 + 1] = b.x; win[d * 5 + 2] = b.y;
        win[d * 5 + 3] = b.z; win[d * 5 + 4] = b.w;
      }
      const float* wb = w1t + ic * 288 + 4 * ocg;       // (ic*9+k)*32 + 4*ocg
#pragma unroll
      for (int ky = 0; ky < 3; ky++)
#pragma unroll
        for (int kx = 0; kx < 3; kx++) {
          const float4 wk = *(const float4*)(wb + (ky * 3 + kx) * 32);
#pragma unroll
          for (int cy = 0; cy < 2; cy++)
#pragma unroll
            for (int cx = 0; cx < 2; cx++) {
              const int p = cy * 2 + cx;
              const float iv = win[(2 * cy + ky) * 5 + (2 * cx + kx)];
              acc[0][p] = fmaf(iv, wk.x, acc[0][p]);
              acc[1][p] = fmaf(iv, wk.y, acc[1][p]);
              acc[2][p] = fmaf(iv, wk.z, acc[2][p]);
              acc[3][p] = fmaf(iv, wk.w, acc[3][p]);
            }
        }
    }
#pragma unroll
    for (int j = 0; j < 4; j++)
#pragma unroll
      for (int p = 0; p < 4; p++)
        acc[j][p] += __shfl_xor(acc[j][p], 32);
    if (icg == 0) {
#pragma unroll
      for (int j = 0; j < 4; j++) {
        const int oc = ocg * 4 + j;
        const float sc = g1[oc] * BN_SCALE, bsj = b1[oc];
        float m = fmaf(acc[j][0], sc, bsj);
        m = fmaxf(m, fmaf(acc[j][1], sc, bsj));
        m = fmaxf(m, fmaf(acc[j][2], sc, bsj));
        m = fmaxf(m, fmaf(acc[j][3], sc, bsj));
        sa1[oc * 124 + (py + 1) * 12 + (px + 1)] = fmaxf(m, 0.f);
      }
    }
  }
  __syncthreads();

  // ---- L2: icg in lane bits 4-5 (ic = icg + 4*ii), shuffle reduce ----
  {
    const int w = t >> 6;
    const int pg = w >> 2, ocb = w & 3;
    const int ocl = lane & 15, icg = lane >> 4;
    const int oc = ocb * 16 + ocl;
    const int pgy = pg >> 1, pgx = pg & 1;
    float acc[16];
#pragma unroll
    for (int p = 0; p < 16; p++) acc[p] = 0.f;
    for (int ii = 0; ii < 8; ii++) {
      const int ic = icg + 4 * ii;
      float wc[9];
      const float* wp = w2t + ic * 576 + oc;
#pragma unroll
      for (int k = 0; k < 9; k++) wc[k] = wp[k * 64];
      float win[6][6];
      const float* bp = sa1 + ic * 124 + 4 * pgy * 12 + 4 * pgx;
#pragma unroll
      for (int d = 0; d < 6; d++) {
        float4 u = *(const float4*)(bp + d * 12);
        float2 v = *(const float2*)(bp + d * 12 + 4);
        win[d][0] = u.x; win[d][1] = u.y; win[d][2] = u.z; win[d][3] = u.w;
        win[d][4] = v.x; win[d][5] = v.y;
      }
#pragma unroll
      for (int u = 0; u < 4; u++)
#pragma unroll
        for (int v = 0; v < 4; v++) {
          float c = acc[u * 4 + v];
#pragma unroll
          for (int ky = 0; ky < 3; ky++)
#pragma unroll
            for (int kx = 0; kx < 3; kx++)
              c = fmaf(win[u + ky][v + kx], wc[ky * 3 + kx], c);
          acc[u * 4 + v] = c;
        }
    }
#pragma unroll
    for (int p = 0; p < 16; p++) {
      acc[p] += __shfl_xor(acc[p], 16);
      acc[p] += __shfl_xor(acc[p], 32);
    }
    if (icg == 0) {
      const float sc = g2[oc] * BN_SCALE, bsj = b2[oc];
#pragma unroll
      for (int cy = 0; cy < 2; cy++)
#pragma unroll
        for (int cx = 0; cx < 2; cx++) {
          float m = -1e30f;
#pragma unroll
          for (int a = 0; a < 2; a++)
#pragma unroll
            for (int b = 0; b < 2; b++)
              m = fmaxf(m, fmaf(acc[(2 * cy + a) * 4 + (2 * cx + b)], sc, bsj));
          sa2[oc * 52 + (1 + 2 * pgy + cy) * 8 + (1 + 2 * pgx + cx)] = fmaxf(m, 0.f);
        }
    }
  }
  __syncthreads();

  // ---- L3: icg in lane bits 3-5 (ic = icg + 8*ii), shuffle reduce ----
  {
    const int w = t >> 6;
    const int ocl = lane & 7, icg = lane >> 3;
    const int oc = w * 8 + ocl;
    float acc[16];
#pragma unroll
    for (int p = 0; p < 16; p++) acc[p] = 0.f;
    for (int ii = 0; ii < 8; ii++) {
      const int ic = icg + 8 * ii;
      float wc[9];
      const float* wp = w3t + ic * 1152 + oc;
#pragma unroll
      for (int k = 0; k < 9; k++) wc[k] = wp[k * 128];
      float win[6][6];
      const float* bp = sa2 + ic * 52;
#pragma unroll
      for (int d = 0; d < 6; d++) {
        float4 u = *(const float4*)(bp + d * 8);
        float2 v = *(const float2*)(bp + d * 8 + 4);
        win[d][0] = u.x; win[d][1] = u.y; win[d][2] = u.z; win[d][3] = u.w;
        win[d][4] = v.x; win[d][5] = v.y;
      }
#pragma unroll
      for (int u = 0; u < 4; u++)
#pragma unroll
        for (int v = 0; v < 4; v++) {
          float c = acc[u * 4 + v];
#pragma unroll
          for (int ky = 0; ky < 3; ky++)
#pragma unroll
            for (int kx = 0; kx < 3; kx++)
              c = fmaf(win[u + ky][v + kx], wc[ky * 3 + kx], c);
          acc[u * 4 + v] = c;
        }
    }
#pragma unroll
    for (int p = 0; p < 16; p++) {
      acc[p] += __shfl_xor(acc[p], 8);
      acc[p] += __shfl_xor(acc[p], 16);
      acc[p] += __shfl_xor(acc[p], 32);
    }
    if (icg == 0) {
      const float sc = g3[oc] * BN_SCALE, bsj = b3[oc];
      float v[4];
#pragma unroll
      for (int pp = 0; pp < 4; pp++) {
        const int py = pp >> 1, px = pp & 1;
        float m = -1e30f;
#pragma unroll
        for (int a = 0; a < 2; a++)
#pragma unroll
          for (int b = 0; b < 2; b++)
            m = fmaxf(m, fmaf(acc[(2 * py + a) * 4 + (2 * px + b)], sc, bsj));
        v[pp] = fmaxf(m, 0.f);
      }
      *(float4*)(sa3 + oc * 4) = make_float4(v[0], v[1], v[2], v[3]);
    }
  }
  __syncthreads();

  // ---- L4: icq in lane bits 4-5 (ic = icq + 4*ii), shuffle reduce ----
  {
    const int w = t >> 6;
    const int ocl = lane & 15, icq = lane >> 4;
    const int oc = w * 16 + ocl;
    float acc[4] = {0.f, 0.f, 0.f, 0.f};
    float wc[9];
    {
      const float* wp = w4t + icq * 2304 + oc;
#pragma unroll
      for (int k = 0; k < 9; k++) wc[k] = wp[k * 256];
    }
    for (int ii = 0; ii < 32; ii++) {
      const int ic = icq + 4 * ii;
      float wn[9];
      if (ii < 31) {
        const float* wp = w4t + (ic + 4) * 2304 + oc;
#pragma unroll
        for (int k = 0; k < 9; k++) wn[k] = wp[k * 256];
      }
      float4 iv = *(const float4*)(sa3 + ic * 4);
#pragma unroll
      for (int py = 0; py < 2; py++)
#pragma unroll
        for (int px = 0; px < 2; px++) {
          float c = acc[py * 2 + px];
          c = fmaf(iv.x, wc[(1 - py) * 3 + (1 - px)], c);
          c = fmaf(iv.y, wc[(1 - py) * 3 + (2 - px)], c);
          c = fmaf(iv.z, wc[(2 - py) * 3 + (1 - px)], c);
          c = fmaf(iv.w, wc[(2 - py) * 3 + (2 - px)], c);
          acc[py * 2 + px] = c;
        }
      if (ii < 31) {
#pragma unroll
        for (int k = 0; k < 9; k++) wc[k] = wn[k];
      }
    }
#pragma unroll
    for (int p = 0; p < 4; p++) {
      acc[p] += __shfl_xor(acc[p], 16);
      acc[p] += __shfl_xor(acc[p], 32);
    }
    if (icq == 0) {
      const float sc = g4[oc] * BN_SCALE, bsj = b4[oc];
      float m = -1e30f;
#pragma unroll
      for (int p = 0; p < 4; p++) m = fmaxf(m, fmaf(acc[p], sc, bsj));
      float r = fmaxf(m, 0.f);
      sft[oc] = r;
      feats_g[(size_t)img * 256 + oc] = r;
    }
  }
  __syncthreads();

  // ---- e: dq in lane bits 4-5 (d = dq + 4*ii), shuffle reduce ----
  if (img < 100) {
    const int w = t >> 6;
    const int c = w * 16 + (lane & 15);
    const int dq = lane >> 4;
    float acc = 0.f;
#pragma unroll 4
    for (int ii = 0; ii < 64; ii++) {
      const int d = dq + 4 * ii;
      acc = fmaf(sft[d], twt[d * 256 + c], acc);
    }
    acc += __shfl_xor(acc, 16);
    acc += __shfl_xor(acc, 32);
    if (dq == 0) e_buf[img * 256 + c] = acc + tb[c];
  }
}

// ---- Kernel 3: 3-iter routing, 10 blocks ----
__global__ void k_routing(const float* __restrict__ e, float* __restrict__ proto) {
  int n = blockIdx.x;
  __shared__ float sb[10], sdc[10], red[4], red2[40], sfc[1];
  int t = threadIdx.x;
  int lane = t & 63, wid = t >> 6;
  float ek[10];
#pragma unroll
  for (int k = 0; k < 10; k++) ek[k] = e[n * 2560 + k * 256 + t];
  if (t < 10) sb[t] = 0.f;
  __syncthreads();
  float cd = 0.f;
  for (int iter = 0; iter < 3; iter++) {
    if (t == 0) {
      float mx = sb[0];
      for (int k = 1; k < 10; k++) mx = fmaxf(mx, sb[k]);
      float sum = 0.f;
      for (int k = 0; k < 10; k++) { float ex = expf(sb[k] - mx); sdc[k] = ex; sum += ex; }
      float inv = 1.f / sum;
      for (int k = 0; k < 10; k++) sdc[k] *= inv;
    }
    __syncthreads();
    cd = 0.f;
#pragma unroll
    for (int k = 0; k < 10; k++) cd = fmaf(sdc[k], ek[k], cd);
    float ss = cd * cd;
#pragma unroll
    for (int off = 32; off > 0; off >>= 1) ss += __shfl_down(ss, off, 64);
    if (lane == 0) red[wid] = ss;
    __syncthreads();
    if (t == 0) {
      float tot = red[0] + red[1] + red[2] + red[3];
      sfc[0] = sqrtf(tot) / (tot + 1.f);
    }
    __syncthreads();
    cd *= sfc[0];
    float pr[10];
#pragma unroll
    for (int k = 0; k < 10; k++) pr[k] = cd * ek[k];
#pragma unroll
    for (int off = 32; off > 0; off >>= 1)
#pragma unroll
      for (int k = 0; k < 10; k++) pr[k] += __shfl_down(pr[k], off, 64);
    if (lane == 0)
#pragma unroll
      for (int k = 0; k < 10; k++) red2[k * 4 + wid] = pr[k];
    __syncthreads();
    if (t < 10) sb[t] += red2[t * 4] + red2[t * 4 + 1] + red2[t * 4 + 2] + red2[t * 4 + 3];
    __syncthreads();
  }
  proto[n * 256 + t] = cd;
}

// ---- Kernel 4: t1 accumulation. 800 blocks (h x 8 c-chunks of 32) ----
__global__ void k_t1(const float* __restrict__ proto, const float* __restrict__ bw,
                     float* __restrict__ t1) {
  __shared__ float pt[384];   // [cl][12], 10 used
  const int b = blockIdx.x;
  const int h = b >> 3, c0 = (b & 7) * 32;
  const int t = threadIdx.x;
  for (int i = t; i < 320; i += 256) {
    int n = i >> 5, cl = i & 31;
    pt[cl * 12 + n] = proto[n * 256 + c0 + cl];
  }
  __syncthreads();
  float acc[10];
#pragma unroll
  for (int n = 0; n < 10; n++) acc[n] = 0.f;
  const float* wp = bw + (size_t)h * 65536 + (size_t)c0 * 256 + t;
#pragma unroll 4
  for (int cl = 0; cl < 32; cl++) {
    float wv = wp[(size_t)cl * 256];
    float4 p0 = *(const float4*)(pt + cl * 12);
    float4 p1 = *(const float4*)(pt + cl * 12 + 4);
    float2 p2 = *(const float2*)(pt + cl * 12 + 8);
    acc[0] = fmaf(p0.x, wv, acc[0]); acc[1] = fmaf(p0.y, wv, acc[1]);
    acc[2] = fmaf(p0.z, wv, acc[2]); acc[3] = fmaf(p0.w, wv, acc[3]);
    acc[4] = fmaf(p1.x, wv, acc[4]); acc[5] = fmaf(p1.y, wv, acc[5]);
    acc[6] = fmaf(p1.z, wv, acc[6]); acc[7] = fmaf(p1.w, wv, acc[7]);
    acc[8] = fmaf(p2.x, wv, acc[8]); acc[9] = fmaf(p2.y, wv, acc[9]);
  }
#pragma unroll
  for (int n = 0; n < 10; n++)
    atomicAdd(&t1[((size_t)n * 100 + h) * 256 + t], acc[n]);
}

// ---- Kernel 5: score partials. 300 blocks (q x 2 h-halves), quad scheme ----
__global__ void k_score(const float* __restrict__ t1, const float* __restrict__ qf,
                        const float* __restrict__ sw, float* __restrict__ s) {
  __shared__ float sq[256];
  __shared__ float vb[2000];   // [lr][4]
  const int q = blockIdx.x >> 1, hh = blockIdx.x & 1;
  const int t = threadIdx.x;
  const int sl = t & 3, quad = t >> 2;
  sq[t] = qf[q * 256 + t];
  __syncthreads();
  const float4* qr = (const float4*)sq;
#pragma unroll
  for (int j = 0; j < 8; j++) {
    int lr = quad + 64 * j;          // local row 0..511
    if (lr < 500) {
      int n = lr / 50, hl = lr % 50;
      const float4* row = (const float4*)(t1 + ((size_t)(n * 100 + hh * 50 + hl)) * 256);
      float acc = 0.f;
#pragma unroll
      for (int d = 0; d < 16; d++) {
        float4 a = row[d * 4 + sl];
        float4 b = qr[d * 4 + sl];
        acc += a.x * b.x + a.y * b.y + a.z * b.z + a.w * b.w;
      }
      vb[lr * 4 + sl] = acc;
    }
  }
  __syncthreads();
  if (t < 10) {
    float sum = 0.f;
    for (int hl = 0; hl < 50; hl++) {
      int lr = t * 50 + hl;
      float d = vb[lr * 4] + vb[lr * 4 + 1] + vb[lr * 4 + 2] + vb[lr * 4 + 3];
      sum = fmaf(fmaxf(d, 0.f), sw[hh * 50 + hl], sum);
    }
    atomicAdd(&s[q * 10 + t], sum);
  }
}

// ---- Kernel 6: log_softmax. 1 block x 256 ----
__global__ void k_lsm(const float* __restrict__ s, const float* __restrict__ sbp,
                      float* __restrict__ out) {
  int q = threadIdx.x;
  if (q >= 150) return;
  float sb0 = sbp[0];
  float v[10];
  float mx = -1e30f;
#pragma unroll
  for (int n = 0; n < 10; n++) {
    v[n] = s[q * 10 + n] + sb0;
    mx = fmaxf(mx, v[n]);
  }
  float sum = 0.f;
#pragma unroll
  for (int n = 0; n < 10; n++) sum += expf(v[n] - mx);
  float lse = mx + logf(sum);
#pragma unroll
  for (int n = 0; n < 10; n++) out[q * 10 + n] = v[n] - lse;
}

extern "C" void kernel_launch(void* const* d_in, const int* in_sizes, int n_in,
                              void* d_out, int out_size, void* d_ws, size_t ws_size,
                              hipStream_t stream) {
  const float* support = (const float*)d_in[0];
  const float* query   = (const float*)d_in[1];
  const float* conv_w[5]; const float* bn_g[5]; const float* bn_b[5];
  for (int i = 0; i < 5; i++) {
    conv_w[i] = (const float*)d_in[2 + 3 * i];
    bn_g[i]   = (const float*)d_in[3 + 3 * i];
    bn_b[i]   = (const float*)d_in[4 + 3 * i];
  }
  const float* trans_w = (const float*)d_in[17];
  const float* trans_b = (const float*)d_in[18];
  const float* bil_w   = (const float*)d_in[19];
  const float* score_w = (const float*)d_in[20];
  const float* score_b = (const float*)d_in[21];
  float* out = (float*)d_out;
  float* ws = (float*)d_ws;

  float* feats = ws + OFF_FEATS;
  float* e_buf = ws + OFF_E;
  float* s_buf = ws + OFF_S;
  float* t1    = ws + OFF_T1;
  float* proto = ws + OFF_PROTO;

  k_prep<<<2793, 256, 0, stream>>>(conv_w[1], conv_w[2], conv_w[3], conv_w[4],
                                   trans_w, ws);
  k_main<<<250, 1024, 0, stream>>>(support, query,
                                   conv_w[0], bn_g[0], bn_b[0],
                                   bn_g[1], bn_b[1], bn_g[2], bn_b[2],
                                   bn_g[3], bn_b[3], bn_g[4], bn_b[4],
                                   trans_b, ws, feats, e_buf);
  k_routing<<<10, 256, 0, stream>>>(e_buf, proto);
  k_t1<<<800, 256, 0, stream>>>(proto, bil_w, t1);
  k_score<<<300, 256, 0, stream>>>(t1, feats + 100 * 256, score_w, s_buf);
  k_lsm<<<1, 256, 0, stream>>>(s_buf, score_b, out);
}

// Round 4
// 205.532 us; speedup vs baseline: 1.0423x; 1.0423x over previous
//
#include <hip/hip_runtime.h>
#include <math.h>

// ---------------------------------------------------------------------------
// RoutingNet round 14 = R12 k_main + R13 coalesced k_prep + a0p XOR swizzle.
//  - R13's shuffle-reduce k_main reverted (shfl = ds_bpermute = LDS pipe;
//    dropped weight prefetch exposed global latency: 68 -> 87 us regression).
//  - a0p swizzle: col' = col ^ (((row>>3)&3)<<3), applied at L0 store and
//    L1 read. Kills the ~8-way span conflict on L1 win reads (the invariant
//    4.8M conflict cycles): conflict set {py,py+2,py+4,py+6} gets 4 distinct
//    XOR values -> 2 lanes/span = free (m136).
//  - k_prep: coalesced-read transposes (R13 form, tail -15 us evidence).
// ---------------------------------------------------------------------------

#define BN_SCALE rsqrtf(1.0f + 1e-5f)

// ws offsets (floats)
#define OFF_FEATS 0
#define OFF_E     64000
#define OFF_S     89600
#define OFF_T1    91136
#define OFF_PROTO 347136
#define OFF_W1T   349696
#define OFF_W2T   354304
#define OFF_W3T   372736
#define OFF_W4T   446464
#define OFF_TWT   741376

// ---- Kernel 1: transposes (coalesced reads) + zero t1,s. 2793 blocks ----
__global__ void k_prep(const float* __restrict__ w1, const float* __restrict__ w2,
                       const float* __restrict__ w3, const float* __restrict__ w4,
                       const float* __restrict__ tw, float* __restrict__ ws) {
  float* w1t = ws + OFF_W1T;
  float* w2t = ws + OFF_W2T;
  float* w3t = ws + OFF_W3T;
  float* w4t = ws + OFF_W4T;
  float* twt = ws + OFF_TWT;
  int i = blockIdx.x * 256 + threadIdx.x;
  if (i < 4608) {                       // w1: 32x16x9, read natural
    int oc = i / 144, r = i % 144;
    int ic = r / 9, tap = r % 9;
    w1t[(ic * 9 + tap) * 32 + oc] = w1[i];
  } else if (i < 23040) {               // w2: 64x32x9
    int m = i - 4608;
    int oc = m / 288, r = m % 288;
    int ic = r / 9, tap = r % 9;
    w2t[(ic * 9 + tap) * 64 + oc] = w2[m];
  } else if (i < 96768) {               // w3: 128x64x9
    int m = i - 23040;
    int oc = m / 576, r = m % 576;
    int ic = r / 9, tap = r % 9;
    w3t[(ic * 9 + tap) * 128 + oc] = w3[m];
  } else if (i < 391680) {              // w4: 256x128x9
    int m = i - 96768;
    int oc = m / 1152, r = m % 1152;
    int ic = r / 9, tap = r % 9;
    w4t[(ic * 9 + tap) * 256 + oc] = w4[m];
  } else if (i < 457216) {              // tw: 256x256, twt[d][c] = tw[c][d]
    int m = i - 391680;
    int r = m >> 8, s = m & 255;
    twt[s * 256 + r] = tw[m];
  } else if (i < 713216) {
    ws[OFF_T1 + (i - 457216)] = 0.f;
  } else if (i < 714716) {
    ws[OFF_S + (i - 713216)] = 0.f;
  }
}

// ---- Kernel 2: whole CNN per image. 250 blocks x 1024 threads ----
__global__ void __launch_bounds__(1024, 4)
k_main(const float* __restrict__ sup, const float* __restrict__ qry,
       const float* __restrict__ w0, const float* __restrict__ g0, const float* __restrict__ b0,
       const float* __restrict__ g1, const float* __restrict__ b1,
       const float* __restrict__ g2, const float* __restrict__ b2,
       const float* __restrict__ g3, const float* __restrict__ b3,
       const float* __restrict__ g4, const float* __restrict__ b4,
       const float* __restrict__ tb, float* __restrict__ ws,
       float* __restrict__ feats_g, float* __restrict__ e_buf) {
  // layout (floats):
  //  [0,3968)      sa1  (32 oc x 10x12 padded, zero borders)
  //  [4096,7424)   sa2  (64 oc x 52)
  //  [7424,7936)   sa3
  //  [7936,8192)   sft
  //  [8192,8580)   gap (zeroed: absorbs a0p row0 left reads)
  //  [8580,28164)  a0p (16 oc x 34x36; interior rows 1..32, cols 0..31
  //                XOR-swizzled col' = col ^ (((row>>3)&3)<<3); pads zero)
  //  [28164,38404) L1R (512 slots x stride 20, conflict-free b128)
  __shared__ __align__(16) float S[38404];   // 153.6 KB, 1 block/CU
  const float* w1t = ws + OFF_W1T;
  const float* w2t = ws + OFF_W2T;
  const float* w3t = ws + OFF_W3T;
  const float* w4t = ws + OFF_W4T;
  const float* twt = ws + OFF_TWT;
  const int img = blockIdx.x;
  const int t = threadIdx.x;
  const int lane = t & 63, wid = t >> 6;
  float* sa1 = S;
  float* sa2 = S + 4096;
  float* sa3 = S + 7424;
  float* sft = S + 7936;
  float* a0p = S + 8580;
  float* RED = S + 8580;
  float* L1R = S + 28164;

  const float* in = (img < 100) ? (sup + (size_t)img * 16384)
                                : (qry + (size_t)(img - 100) * 16384);

  // zero [0, 28164) via float4 (7041 b128s); L1R needs no init
  {
    float4* S4 = (float4*)S;
    const float4 z4 = make_float4(0.f, 0.f, 0.f, 0.f);
    for (int i = t; i < 7041; i += 1024) S4[i] = z4;
  }
  __syncthreads();

  // ---- L0: direct-global, 2 oc per wave x half of pooled rows ----
  {
    const int ocp = wid & 7;            // oc pair: 2*ocp, 2*ocp+1
    const int rhalf = wid >> 3;         // pooled rows [16*rhalf, 16*rhalf+16)
    const int oc0 = 2 * ocp, oc1 = oc0 + 1;
    float wv0[9], wv1[9];
#pragma unroll
    for (int k = 0; k < 9; k++) { wv0[k] = w0[oc0 * 9 + k]; wv1[k] = w0[oc1 * 9 + k]; }
    const float sc0 = g0[oc0] * BN_SCALE, bs0 = b0[oc0];
    const float sc1 = g0[oc1] * BN_SCALE, bs1 = b0[oc1];
#pragma unroll
    for (int it2 = 0; it2 < 2; it2++) {
      const int s2 = rhalf * 128 + it2 * 64 + lane;   // strip id
      const int pr = s2 >> 3, pcq = s2 & 7;           // pooled row, 4-col strip
      float ac0[2][8], ac1[2][8];
#pragma unroll
      for (int j = 0; j < 8; j++) {
        ac0[0][j] = 0.f; ac0[1][j] = 0.f; ac1[0][j] = 0.f; ac1[1][j] = 0.f;
      }
#pragma unroll
      for (int d = 0; d < 5; d++) {
        const int ir = 4 * pr - 1 + d;                // only -1 possible OOB
        float x[17];                                  // cols 16*pcq-1 .. +15
        if (ir >= 0) {
          const float* rp = in + ir * 128 + 16 * pcq;
          float4 q0 = ((const float4*)rp)[0];
          float4 q1 = ((const float4*)rp)[1];
          float4 q2 = ((const float4*)rp)[2];
          float4 q3 = ((const float4*)rp)[3];
          x[0] = (pcq > 0) ? rp[-1] : 0.f;
          x[1] = q0.x;  x[2] = q0.y;  x[3] = q0.z;  x[4] = q0.w;
          x[5] = q1.x;  x[6] = q1.y;  x[7] = q1.z;  x[8] = q1.w;
          x[9] = q2.x;  x[10] = q2.y; x[11] = q2.z; x[12] = q2.w;
          x[13] = q3.x; x[14] = q3.y; x[15] = q3.z; x[16] = q3.w;
        } else {
#pragma unroll
          for (int k = 0; k < 17; k++) x[k] = 0.f;
        }
        if (d <= 2) {
          const int b9 = d * 3;
#pragma unroll
          for (int j = 0; j < 8; j++) {
            ac0[0][j] = fmaf(x[2 * j + 2], wv0[b9 + 2],
                        fmaf(x[2 * j + 1], wv0[b9 + 1],
                        fmaf(x[2 * j],     wv0[b9],     ac0[0][j])));
            ac1[0][j] = fmaf(x[2 * j + 2], wv1[b9 + 2],
                        fmaf(x[2 * j + 1], wv1[b9 + 1],
                        fmaf(x[2 * j],     wv1[b9],     ac1[0][j])));
          }
        }
        if (d >= 2) {
          const int b9 = (d - 2) * 3;
#pragma unroll
          for (int j = 0; j < 8; j++) {
            ac0[1][j] = fmaf(x[2 * j + 2], wv0[b9 + 2],
                        fmaf(x[2 * j + 1], wv0[b9 + 1],
                        fmaf(x[2 * j],     wv0[b9],     ac0[1][j])));
            ac1[1][j] = fmaf(x[2 * j + 2], wv1[b9 + 2],
                        fmaf(x[2 * j + 1], wv1[b9 + 1],
                        fmaf(x[2 * j],     wv1[b9],     ac1[1][j])));
          }
        }
      }
      {
        const int row = pr + 1;
        const int swz = ((row >> 3) & 3) << 3;
        const int colp = (4 * pcq) ^ swz;        // swizzled col, stays in 0..31
        float v[4];
#pragma unroll
        for (int p = 0; p < 4; p++) {
          float m = fmaf(ac0[0][2 * p], sc0, bs0);
          m = fmaxf(m, fmaf(ac0[0][2 * p + 1], sc0, bs0));
          m = fmaxf(m, fmaf(ac0[1][2 * p], sc0, bs0));
          m = fmaxf(m, fmaf(ac0[1][2 * p + 1], sc0, bs0));
          v[p] = fmaxf(m, 0.f);
        }
        *(float4*)(a0p + oc0 * 1224 + row * 36 + colp) =
            make_float4(v[0], v[1], v[2], v[3]);
#pragma unroll
        for (int p = 0; p < 4; p++) {
          float m = fmaf(ac1[0][2 * p], sc1, bs1);
          m = fmaxf(m, fmaf(ac1[0][2 * p + 1], sc1, bs1));
          m = fmaxf(m, fmaf(ac1[1][2 * p], sc1, bs1));
          m = fmaxf(m, fmaf(ac1[1][2 * p + 1], sc1, bs1));
          v[p] = fmaxf(m, 0.f);
        }
        *(float4*)(a0p + oc1 * 1224 + row * 36 + colp) =
            make_float4(v[0], v[1], v[2], v[3]);
      }
    }
  }
  __syncthreads();

  // ---- L1: 2-way ic-split, 4 oc per thread (float4 weights), swizzled read --
  {
    const int pos = t & 63, py = pos >> 3, px = pos & 7;
    const int ocg = (t >> 6) & 7, icg = t >> 9;
    // precompute swizzled per-d offsets (plane-relative)
    int offb[5], offa[5];
#pragma unroll
    for (int d = 0; d < 5; d++) {
      const int row = 4 * py + d;
      const int swz = ((row >> 3) & 3) << 3;
      offb[d] = row * 36 + ((4 * px) ^ swz);
      offa[d] = (px > 0) ? (row * 36 + ((4 * px - 4) ^ swz))
                         : (row * 36 - 4);      // unwritten pad/gap = zeros
    }
    float acc[4][4];
#pragma unroll
    for (int j = 0; j < 4; j++)
#pragma unroll
      for (int p = 0; p < 4; p++) acc[j][p] = 0.f;
    const int ic0 = icg * 8;
    for (int ii = 0; ii < 8; ii++) {
      const int ic = ic0 + ii;
      float4 wq[9];
#pragma unroll
      for (int k = 0; k < 9; k++)
        wq[k] = *(const float4*)(w1t + (ic * 9 + k) * 32 + 4 * ocg);
      float win[25];
      const float* pl = a0p + ic * 1224;
#pragma unroll
      for (int d = 0; d < 5; d++) {
        float4 a = *(const float4*)(pl + offa[d]);
        float4 b = *(const float4*)(pl + offb[d]);
        win[d * 5 + 0] = a.w;
        win[d * 5 + 1] = b.x; win[d * 5 + 2] = b.y;
        win[d * 5 + 3] = b.z; win[d * 5 + 4] = b.w;
      }
#pragma unroll
      for (int cy = 0; cy < 2; cy++)
#pragma unroll
        for (int cx = 0; cx < 2; cx++) {
          const int p = cy * 2 + cx;
#pragma unroll
          for (int ky = 0; ky < 3; ky++)
#pragma unroll
            for (int kx = 0; kx < 3; kx++) {
              const float iv = win[(2 * cy + ky) * 5 + (2 * cx + kx)];
              const float4 wk = wq[ky * 3 + kx];
              acc[0][p] = fmaf(iv, wk.x, acc[0][p]);
              acc[1][p] = fmaf(iv, wk.y, acc[1][p]);
              acc[2][p] = fmaf(iv, wk.z, acc[2][p]);
              acc[3][p] = fmaf(iv, wk.w, acc[3][p]);
            }
        }
    }
    const int slot = ocg * 64 + pos;     // lane stride = 20 floats: conflict-free
    if (icg == 1) {
      float* wp2 = L1R + slot * 20;
#pragma unroll
      for (int j = 0; j < 4; j++)
        *(float4*)(wp2 + j * 4) = make_float4(acc[j][0], acc[j][1], acc[j][2], acc[j][3]);
    }
    __syncthreads();
    if (icg == 0) {
      const float* rp2 = L1R + slot * 20;
#pragma unroll
      for (int j = 0; j < 4; j++) {
        float4 o = *(const float4*)(rp2 + j * 4);
        const int oc = ocg * 4 + j;
        const float sc = g1[oc] * BN_SCALE, bsj = b1[oc];
        float m = fmaf(acc[j][0] + o.x, sc, bsj);
        m = fmaxf(m, fmaf(acc[j][1] + o.y, sc, bsj));
        m = fmaxf(m, fmaf(acc[j][2] + o.z, sc, bsj));
        m = fmaxf(m, fmaf(acc[j][3] + o.w, sc, bsj));
        sa1[oc * 124 + (py + 1) * 12 + (px + 1)] = fmaxf(m, 0.f);
      }
    }
  }
  __syncthreads();

  // ---- L2 (pipelined) ----
  {
    int oc = t & 63, icg = (t >> 6) & 3, pg = t >> 8;
    int pgy = pg >> 1, pgx = pg & 1;
    float acc[16];
#pragma unroll
    for (int p = 0; p < 16; p++) acc[p] = 0.f;
    float wc[9];
    {
      const float* wp = w2t + (icg * 8) * 576 + oc;
#pragma unroll
      for (int k = 0; k < 9; k++) wc[k] = wp[k * 64];
    }
    for (int ii = 0; ii < 8; ii++) {
      int ic = icg * 8 + ii;
      float wn[9];
      if (ii < 7) {
        const float* wp = w2t + (ic + 1) * 576 + oc;
#pragma unroll
        for (int k = 0; k < 9; k++) wn[k] = wp[k * 64];
      }
      float win[6][6];
      const float* bp = sa1 + ic * 124 + 4 * pgy * 12 + 4 * pgx;
#pragma unroll
      for (int d = 0; d < 6; d++) {
        float4 u = *(const float4*)(bp + d * 12);
        float2 v = *(const float2*)(bp + d * 12 + 4);
        win[d][0] = u.x; win[d][1] = u.y; win[d][2] = u.z; win[d][3] = u.w;
        win[d][4] = v.x; win[d][5] = v.y;
      }
#pragma unroll
      for (int u = 0; u < 4; u++)
#pragma unroll
        for (int v = 0; v < 4; v++) {
          float c = acc[u * 4 + v];
#pragma unroll
          for (int ky = 0; ky < 3; ky++)
#pragma unroll
            for (int kx = 0; kx < 3; kx++)
              c = fmaf(win[u + ky][v + kx], wc[ky * 3 + kx], c);
          acc[u * 4 + v] = c;
        }
      if (ii < 7) {
#pragma unroll
        for (int k = 0; k < 9; k++) wc[k] = wn[k];
      }
    }
#pragma unroll
    for (int j = 0; j < 16; j++) RED[j * 1024 + icg * 256 + pg * 64 + oc] = acc[j];
  }
  __syncthreads();
  if (t < 256) {
    int oc = t & 63, pg = t >> 6;
    int pgy = pg >> 1, pgx = pg & 1;
    float sc = g2[oc] * BN_SCALE, bsj = b2[oc];
#pragma unroll
    for (int cy = 0; cy < 2; cy++)
#pragma unroll
      for (int cx = 0; cx < 2; cx++) {
        float m = -1e30f;
#pragma unroll
        for (int a = 0; a < 2; a++)
#pragma unroll
          for (int b = 0; b < 2; b++) {
            int j = (2 * cy + a) * 4 + (2 * cx + b);
            float v = RED[j * 1024 + pg * 64 + oc] + RED[j * 1024 + 256 + pg * 64 + oc]
                    + RED[j * 1024 + 512 + pg * 64 + oc] + RED[j * 1024 + 768 + pg * 64 + oc];
            m = fmaxf(m, fmaf(v, sc, bsj));
          }
        sa2[oc * 52 + (1 + 2 * pgy + cy) * 8 + (1 + 2 * pgx + cx)] = fmaxf(m, 0.f);
      }
  }
  __syncthreads();

  // ---- L3 (pipelined) ----
  {
    int oc = t & 127, icg = t >> 7;
    float acc[16];
#pragma unroll
    for (int p = 0; p < 16; p++) acc[p] = 0.f;
    float wc[9];
    {
      const float* wp = w3t + (icg * 8) * 1152 + oc;
#pragma unroll
      for (int k = 0; k < 9; k++) wc[k] = wp[k * 128];
    }
    for (int ii = 0; ii < 8; ii++) {
      int ic = icg * 8 + ii;
      float wn[9];
      if (ii < 7) {
        const float* wp = w3t + (ic + 1) * 1152 + oc;
#pragma unroll
        for (int k = 0; k < 9; k++) wn[k] = wp[k * 128];
      }
      float win[6][6];
      const float* bp = sa2 + ic * 52;
#pragma unroll
      for (int d = 0; d < 6; d++) {
        float4 u = *(const float4*)(bp + d * 8);
        float2 v = *(const float2*)(bp + d * 8 + 4);
        win[d][0] = u.x; win[d][1] = u.y; win[d][2] = u.z; win[d][3] = u.w;
        win[d][4] = v.x; win[d][5] = v.y;
      }
#pragma unroll
      for (int u = 0; u < 4; u++)
#pragma unroll
        for (int v = 0; v < 4; v++) {
          float c = acc[u * 4 + v];
#pragma unroll
          for (int ky = 0; ky < 3; ky++)
#pragma unroll
            for (int kx = 0; kx < 3; kx++)
              c = fmaf(win[u + ky][v + kx], wc[ky * 3 + kx], c);
          acc[u * 4 + v] = c;
        }
      if (ii < 7) {
#pragma unroll
        for (int k = 0; k < 9; k++) wc[k] = wn[k];
      }
    }
#pragma unroll
    for (int j = 0; j < 16; j++) RED[j * 1024 + icg * 128 + oc] = acc[j];
  }
  __syncthreads();
  if (t < 512) {
    int oc = t & 127, pp = t >> 7;
    int py = pp >> 1, px = pp & 1;
    float sc = g3[oc] * BN_SCALE, bsj = b3[oc];
    float m = -1e30f;
#pragma unroll
    for (int a = 0; a < 2; a++)
#pragma unroll
      for (int b = 0; b < 2; b++) {
        int j = (2 * py + a) * 4 + (2 * px + b);
        float v = 0.f;
#pragma unroll
        for (int g = 0; g < 8; g++) v += RED[j * 1024 + g * 128 + oc];
        m = fmaxf(m, fmaf(v, sc, bsj));
      }
    sa3[oc * 4 + pp] = fmaxf(m, 0.f);
  }
  __syncthreads();

  // ---- L4 (pipelined) ----
  {
    int oc = t & 255, icq = t >> 8;
    float acc[4] = {0.f, 0.f, 0.f, 0.f};
    float wc[9];
    {
      const float* wp = w4t + (icq * 32) * 2304 + oc;
#pragma unroll
      for (int k = 0; k < 9; k++) wc[k] = wp[k * 256];
    }
    for (int ii = 0; ii < 32; ii++) {
      int ic = icq * 32 + ii;
      float wn[9];
      if (ii < 31) {
        const float* wp = w4t + (ic + 1) * 2304 + oc;
#pragma unroll
        for (int k = 0; k < 9; k++) wn[k] = wp[k * 256];
      }
      float4 iv = *(const float4*)(sa3 + ic * 4);
#pragma unroll
      for (int py = 0; py < 2; py++)
#pragma unroll
        for (int px = 0; px < 2; px++) {
          float c = acc[py * 2 + px];
          c = fmaf(iv.x, wc[(1 - py) * 3 + (1 - px)], c);
          c = fmaf(iv.y, wc[(1 - py) * 3 + (2 - px)], c);
          c = fmaf(iv.z, wc[(2 - py) * 3 + (1 - px)], c);
          c = fmaf(iv.w, wc[(2 - py) * 3 + (2 - px)], c);
          acc[py * 2 + px] = c;
        }
      if (ii < 31) {
#pragma unroll
        for (int k = 0; k < 9; k++) wc[k] = wn[k];
      }
    }
    if (icq) {
#pragma unroll
      for (int p = 0; p < 4; p++) RED[((icq - 1) * 256 + oc) * 4 + p] = acc[p];
    }
    __syncthreads();
    if (icq == 0) {
      float sc = g4[oc] * BN_SCALE, bsj = b4[oc];
      float m = -1e30f;
#pragma unroll
      for (int p = 0; p < 4; p++) {
        float v = acc[p] + RED[oc * 4 + p] + RED[(256 + oc) * 4 + p] + RED[(512 + oc) * 4 + p];
        m = fmaxf(m, fmaf(v, sc, bsj));
      }
      float r = fmaxf(m, 0.f);
      sft[oc] = r;
      feats_g[(size_t)img * 256 + oc] = r;
    }
  }
  __syncthreads();

  // ---- e ----
  if (img < 100) {
    int c = t & 255, dq = t >> 8;
    float acc = 0.f;
    float wv = twt[(dq * 64) * 256 + c];
#pragma unroll 4
    for (int ii = 0; ii < 64; ii++) {
      int d = dq * 64 + ii;
      float wnext = (ii < 63) ? twt[(d + 1) * 256 + c] : 0.f;
      acc = fmaf(sft[d], wv, acc);
      wv = wnext;
    }
    if (dq) RED[(dq - 1) * 256 + c] = acc;
    __syncthreads();
    if (dq == 0)
      e_buf[img * 256 + c] = acc + RED[c] + RED[256 + c] + RED[512 + c] + tb[c];
  }
}

// ---- Kernel 3: 3-iter routing, 10 blocks ----
__global__ void k_routing(const float* __restrict__ e, float* __restrict__ proto) {
  int n = blockIdx.x;
  __shared__ float sb[10], sdc[10], red[4], red2[40], sfc[1];
  int t = threadIdx.x;
  int lane = t & 63, wid = t >> 6;
  float ek[10];
#pragma unroll
  for (int k = 0; k < 10; k++) ek[k] = e[n * 2560 + k * 256 + t];
  if (t < 10) sb[t] = 0.f;
  __syncthreads();
  float cd = 0.f;
  for (int iter = 0; iter < 3; iter++) {
    if (t == 0) {
      float mx = sb[0];
      for (int k = 1; k < 10; k++) mx = fmaxf(mx, sb[k]);
      float sum = 0.f;
      for (int k = 0; k < 10; k++) { float ex = expf(sb[k] - mx); sdc[k] = ex; sum += ex; }
      float inv = 1.f / sum;
      for (int k = 0; k < 10; k++) sdc[k] *= inv;
    }
    __syncthreads();
    cd = 0.f;
#pragma unroll
    for (int k = 0; k < 10; k++) cd = fmaf(sdc[k], ek[k], cd);
    float ss = cd * cd;
#pragma unroll
    for (int off = 32; off > 0; off >>= 1) ss += __shfl_down(ss, off, 64);
    if (lane == 0) red[wid] = ss;
    __syncthreads();
    if (t == 0) {
      float tot = red[0] + red[1] + red[2] + red[3];
      sfc[0] = sqrtf(tot) / (tot + 1.f);
    }
    __syncthreads();
    cd *= sfc[0];
    float pr[10];
#pragma unroll
    for (int k = 0; k < 10; k++) pr[k] = cd * ek[k];
#pragma unroll
    for (int off = 32; off > 0; off >>= 1)
#pragma unroll
      for (int k = 0; k < 10; k++) pr[k] += __shfl_down(pr[k], off, 64);
    if (lane == 0)
#pragma unroll
      for (int k = 0; k < 10; k++) red2[k * 4 + wid] = pr[k];
    __syncthreads();
    if (t < 10) sb[t] += red2[t * 4] + red2[t * 4 + 1] + red2[t * 4 + 2] + red2[t * 4 + 3];
    __syncthreads();
  }
  proto[n * 256 + t] = cd;
}

// ---- Kernel 4: t1 accumulation. 800 blocks (h x 8 c-chunks of 32) ----
__global__ void k_t1(const float* __restrict__ proto, const float* __restrict__ bw,
                     float* __restrict__ t1) {
  __shared__ float pt[384];   // [cl][12], 10 used
  const int b = blockIdx.x;
  const int h = b >> 3, c0 = (b & 7) * 32;
  const int t = threadIdx.x;
  for (int i = t; i < 320; i += 256) {
    int n = i >> 5, cl = i & 31;
    pt[cl * 12 + n] = proto[n * 256 + c0 + cl];
  }
  __syncthreads();
  float acc[10];
#pragma unroll
  for (int n = 0; n < 10; n++) acc[n] = 0.f;
  const float* wp = bw + (size_t)h * 65536 + (size_t)c0 * 256 + t;
#pragma unroll 4
  for (int cl = 0; cl < 32; cl++) {
    float wv = wp[(size_t)cl * 256];
    float4 p0 = *(const float4*)(pt + cl * 12);
    float4 p1 = *(const float4*)(pt + cl * 12 + 4);
    float2 p2 = *(const float2*)(pt + cl * 12 + 8);
    acc[0] = fmaf(p0.x, wv, acc[0]); acc[1] = fmaf(p0.y, wv, acc[1]);
    acc[2] = fmaf(p0.z, wv, acc[2]); acc[3] = fmaf(p0.w, wv, acc[3]);
    acc[4] = fmaf(p1.x, wv, acc[4]); acc[5] = fmaf(p1.y, wv, acc[5]);
    acc[6] = fmaf(p1.z, wv, acc[6]); acc[7] = fmaf(p1.w, wv, acc[7]);
    acc[8] = fmaf(p2.x, wv, acc[8]); acc[9] = fmaf(p2.y, wv, acc[9]);
  }
#pragma unroll
  for (int n = 0; n < 10; n++)
    atomicAdd(&t1[((size_t)n * 100 + h) * 256 + t], acc[n]);
}

// ---- Kernel 5: score partials. 300 blocks (q x 2 h-halves), quad scheme ----
__global__ void k_score(const float* __restrict__ t1, const float* __restrict__ qf,
                        const float* __restrict__ sw, float* __restrict__ s) {
  __shared__ float sq[256];
  __shared__ float vb[2000];   // [lr][4]
  const int q = blockIdx.x >> 1, hh = blockIdx.x & 1;
  const int t = threadIdx.x;
  const int sl = t & 3, quad = t >> 2;
  sq[t] = qf[q * 256 + t];
  __syncthreads();
  const float4* qr = (const float4*)sq;
#pragma unroll
  for (int j = 0; j < 8; j++) {
    int lr = quad + 64 * j;          // local row 0..511
    if (lr < 500) {
      int n = lr / 50, hl = lr % 50;
      const float4* row = (const float4*)(t1 + ((size_t)(n * 100 + hh * 50 + hl)) * 256);
      float acc = 0.f;
#pragma unroll
      for (int d = 0; d < 16; d++) {
        float4 a = row[d * 4 + sl];
        float4 b = qr[d * 4 + sl];
        acc += a.x * b.x + a.y * b.y + a.z * b.z + a.w * b.w;
      }
      vb[lr * 4 + sl] = acc;
    }
  }
  __syncthreads();
  if (t < 10) {
    float sum = 0.f;
    for (int hl = 0; hl < 50; hl++) {
      int lr = t * 50 + hl;
      float d = vb[lr * 4] + vb[lr * 4 + 1] + vb[lr * 4 + 2] + vb[lr * 4 + 3];
      sum = fmaf(fmaxf(d, 0.f), sw[hh * 50 + hl], sum);
    }
    atomicAdd(&s[q * 10 + t], sum);
  }
}

// ---- Kernel 6: log_softmax. 1 block x 256 ----
__global__ void k_lsm(const float* __restrict__ s, const float* __restrict__ sbp,
                      float* __restrict__ out) {
  int q = threadIdx.x;
  if (q >= 150) return;
  float sb0 = sbp[0];
  float v[10];
  float mx = -1e30f;
#pragma unroll
  for (int n = 0; n < 10; n++) {
    v[n] = s[q * 10 + n] + sb0;
    mx = fmaxf(mx, v[n]);
  }
  float sum = 0.f;
#pragma unroll
  for (int n = 0; n < 10; n++) sum += expf(v[n] - mx);
  float lse = mx + logf(sum);
#pragma unroll
  for (int n = 0; n < 10; n++) out[q * 10 + n] = v[n] - lse;
}

extern "C" void kernel_launch(void* const* d_in, const int* in_sizes, int n_in,
                              void* d_out, int out_size, void* d_ws, size_t ws_size,
                              hipStream_t stream) {
  const float* support = (const float*)d_in[0];
  const float* query   = (const float*)d_in[1];
  const float* conv_w[5]; const float* bn_g[5]; const float* bn_b[5];
  for (int i = 0; i < 5; i++) {
    conv_w[i] = (const float*)d_in[2 + 3 * i];
    bn_g[i]   = (const float*)d_in[3 + 3 * i];
    bn_b[i]   = (const float*)d_in[4 + 3 * i];
  }
  const float* trans_w = (const float*)d_in[17];
  const float* trans_b = (const float*)d_in[18];
  const float* bil_w   = (const float*)d_in[19];
  const float* score_w = (const float*)d_in[20];
  const float* score_b = (const float*)d_in[21];
  float* out = (float*)d_out;
  float* ws = (float*)d_ws;

  float* feats = ws + OFF_FEATS;
  float* e_buf = ws + OFF_E;
  float* s_buf = ws + OFF_S;
  float* t1    = ws + OFF_T1;
  float* proto = ws + OFF_PROTO;

  k_prep<<<2793, 256, 0, stream>>>(conv_w[1], conv_w[2], conv_w[3], conv_w[4],
                                   trans_w, ws);
  k_main<<<250, 1024, 0, stream>>>(support, query,
                                   conv_w[0], bn_g[0], bn_b[0],
                                   bn_g[1], bn_b[1], bn_g[2], bn_b[2],
                                   bn_g[3], bn_b[3], bn_g[4], bn_b[4],
                                   trans_b, ws, feats, e_buf);
  k_routing<<<10, 256, 0, stream>>>(e_buf, proto);
  k_t1<<<800, 256, 0, stream>>>(proto, bil_w, t1);
  k_score<<<300, 256, 0, stream>>>(t1, feats + 100 * 256, score_w, s_buf);
  k_lsm<<<1, 256, 0, stream>>>(s_buf, score_b, out);
}